// Round 7
// baseline (512.627 us; speedup 1.0000x reference)
//
#include <hip/hip_runtime.h>
#include <stdint.h>

// Problem constants (from reference): D1=3, S=384, B=32, N=65536
#define NPTS 65536
#define NB   32
#define SS   384

// RN(1/3) in f32 = 0x3EAAAAAB
#define C3INV 0.333333343267440796f

// Strict (non-contractable) f32 mul/add via inline asm — the compiler's
// default -ffp-contract=fast otherwise fuses mul+add chains (R2/R3/R4
// compiled identical). XLA/naive-C einsum for K=3 is plain mul/add.
__device__ __forceinline__ float fmul_strict(float a, float b) {
    float r;
    asm volatile("v_mul_f32 %0, %1, %2" : "=v"(r) : "v"(a), "v"(b));
    return r;
}
__device__ __forceinline__ float fadd_strict(float a, float b) {
    float r;
    asm volatile("v_add_f32 %0, %1, %2" : "=v"(r) : "v"(a), "v"(b));
    return r;
}

// Per-point lattice computation, f32 throughout.
// KEY CHANGE (R7): greedy = round(e * (1/3)) * 3 — reciprocal MULTIPLY, not
// IEEE divide. XLA's algebraic simplifier rewrites x/const -> x*(1/const);
// the np reference pipeline's decision boundaries match recip-mul, not div
// (div-vs-recip differs by ~1ulp -> ~50 rint flips over 4M decisions, which
// quantitatively explains the 1.37/2.05/2.59 absmax pattern of R4/R5/R6).
// Downstream of greedy everything is exact integer / Sterbenz-exact.
__device__ __forceinline__ void lattice_point(
    const float* __restrict__ t,   // 9 floats, row-major trans_mat[b]
    float p0, float p1, float p2,
    int& gi0, int& gi1, int& rc0, int& rc1)
{
    float e0 = fadd_strict(fadd_strict(fmul_strict(t[0], p0), fmul_strict(t[1], p1)), fmul_strict(t[2], p2));
    float e1 = fadd_strict(fadd_strict(fmul_strict(t[3], p0), fmul_strict(t[4], p1)), fmul_strict(t[5], p2));
    float e2 = fadd_strict(fadd_strict(fmul_strict(t[6], p0), fmul_strict(t[7], p1)), fmul_strict(t[8], p2));

    // greedy = round(e * (1/3)) * 3   (rintf == half-even == np/jnp round)
    float g0 = __fmul_rn(rintf(__fmul_rn(e0, C3INV)), 3.0f);
    float g1 = __fmul_rn(rintf(__fmul_rn(e1, C3INV)), 3.0f);
    float g2 = __fmul_rn(rintf(__fmul_rn(e2, C3INV)), 3.0f);

    // emg = elevated - greedy (exact); rank = stable descending argsort pos
    float m0 = e0 - g0, m1 = e1 - g1, m2 = e2 - g2;
    int r0 = (int)(m1 > m0) + (int)(m2 > m0);
    int r1 = (int)(m0 >= m1) + (int)(m2 > m1);
    // (rank of channel 2 never affects channels 0/1 downstream)

    gi0 = (int)g0;
    gi1 = (int)g1;

    // rs = (g0+g1+g2)/3 : exact integer (sum is a multiple of 3; recip-mul
    // in the ref also yields the exact integer for these magnitudes)
    const int irs = (gi0 + gi1 + (int)g2) / 3;

    // cond/sign adjustment (per-channel independent)
    if (irs > 0) {
        if (r0 >= 3 - irs) { gi0 -= 3; r0 -= 3; }
        if (r1 >= 3 - irs) { gi1 -= 3; r1 -= 3; }
    } else if (irs < 0) {
        if (r0 < -irs) { gi0 += 3; r0 += 3; }
        if (r1 < -irs) { gi1 += 3; r1 += 3; }
    }
    r0 += irs;
    r1 += irs;

    // Gather row for CANONICAL[rank]: wrap negative once, clamp to [0,2].
    // (clamp-only vs wrap-then-clamp verified output-identical on this data)
    // min_k CANONICAL[row][k] == -row  (rows: [0,1,2],[0,1,-1],[0,-2,-1])
    if (r0 < 0) r0 += 3;
    if (r1 < 0) r1 += 3;
    rc0 = min(2, max(0, r0));
    rc1 = min(2, max(0, r1));
}

// Pass A: per-batch min over n,k of keys = min over n of (greedy_c - row_c)
__global__ __launch_bounds__(256) void kmin_kernel(
    const float* __restrict__ pc, const float* __restrict__ tmg,
    int* __restrict__ mins)
{
    const int b = blockIdx.y;
    const int n = blockIdx.x * 256 + threadIdx.x;

    __shared__ float t[9];
    if (threadIdx.x < 9) t[threadIdx.x] = tmg[b * 9 + threadIdx.x];
    __syncthreads();

    const float p0 = pc[(b * 3 + 0) * NPTS + n];
    const float p1 = pc[(b * 3 + 1) * NPTS + n];
    const float p2 = pc[(b * 3 + 2) * NPTS + n];

    int gi0, gi1, rc0, rc1;
    lattice_point(t, p0, p1, p2, gi0, gi1, rc0, rc1);

    int km0 = gi0 - rc0;
    int km1 = gi1 - rc1;

    // wave (64-lane) min reduce
#pragma unroll
    for (int off = 32; off > 0; off >>= 1) {
        km0 = min(km0, __shfl_down(km0, off));
        km1 = min(km1, __shfl_down(km1, off));
    }
    __shared__ int s0[4], s1[4];
    const int wid = threadIdx.x >> 6;
    const int lid = threadIdx.x & 63;
    if (lid == 0) { s0[wid] = km0; s1[wid] = km1; }
    __syncthreads();
    if (threadIdx.x == 0) {
        int m0 = min(min(s0[0], s0[1]), min(s0[2], s0[3]));
        int m1 = min(min(s1[0], s1[1]), min(s1[2], s1[3]));
        atomicMin(&mins[b * 2 + 0], m0);
        atomicMin(&mins[b * 2 + 1], m1);
    }
}

// Pass B: recompute the point, bin it, scatter-add the 3 feature channels.
// (binning uses only adjusted greedy: CANONICAL column 0 is all zeros, and
// bary == [1,0,0] exactly — the reference's two scatter-adds cancel.)
__global__ __launch_bounds__(256) void splat_kernel(
    const float* __restrict__ pc, const float* __restrict__ feat,
    const float* __restrict__ tmg, const int* __restrict__ mins,
    float* __restrict__ out)
{
    const int b = blockIdx.y;
    const int n = blockIdx.x * 256 + threadIdx.x;

    __shared__ float t[9];
    if (threadIdx.x < 9) t[threadIdx.x] = tmg[b * 9 + threadIdx.x];
    __syncthreads();

    const float p0 = pc[(b * 3 + 0) * NPTS + n];
    const float p1 = pc[(b * 3 + 1) * NPTS + n];
    const float p2 = pc[(b * 3 + 2) * NPTS + n];

    int gi0, gi1, rc0, rc1;
    lattice_point(t, p0, p1, p2, gi0, gi1, rc0, rc1);

    const int off0 = mins[b * 2 + 0];
    const int off1 = mins[b * 2 + 1];
    const int c0 = gi0 - off0;  // >= 0: offset is a global min incl. all k keys
    const int c1 = gi1 - off1;

    if ((unsigned)c0 < SS && (unsigned)c1 < SS) {
        // c0 == pick0 + 3*y exactly (c0 ≡ pick0 mod 3), so y = c0/3
        const int y = c0 / 3;
        const int x = c1 / 3;
        float* o = out + (((size_t)(b * 128 + y) * 128 + x) * 3);
        atomicAdd(o + 0, feat[(b * 3 + 0) * NPTS + n]);
        atomicAdd(o + 1, feat[(b * 3 + 1) * NPTS + n]);
        atomicAdd(o + 2, feat[(b * 3 + 2) * NPTS + n]);
    }
}

extern "C" void kernel_launch(void* const* d_in, const int* in_sizes, int n_in,
                              void* d_out, int out_size, void* d_ws, size_t ws_size,
                              hipStream_t stream) {
    const float* pc   = (const float*)d_in[0];  // (32,3,65536) f32
    const float* feat = (const float*)d_in[1];  // (32,3,65536) f32
    const float* tm   = (const float*)d_in[2];  // (32,3,3) f32
    float* out = (float*)d_out;                 // (32,128,128,3) f32
    int* mins = (int*)d_ws;                     // 64 ints

    // init mins to ~INT_MAX (0x7F7F7F7F), zero the output
    hipMemsetAsync(mins, 0x7F, 64 * sizeof(int), stream);
    hipMemsetAsync(out, 0, (size_t)out_size * sizeof(float), stream);

    dim3 grid(NPTS / 256, NB);
    kmin_kernel<<<grid, 256, 0, stream>>>(pc, tm, mins);
    splat_kernel<<<grid, 256, 0, stream>>>(pc, feat, tm, mins, out);
}

// Round 8
// 301.572 us; speedup vs baseline: 1.6998x; 1.6998x over previous
//
#include <hip/hip_runtime.h>
#include <stdint.h>

// Problem constants (from reference): D1=3, S=384, B=32, N=65536
#define NPTS 65536
#define NB   32
#define SS   384

// RN(1/3) in f32 = 0x3EAAAAAB
#define C3INV 0.333333343267440796f

// ---- LOCKED NUMERICS (R7, passed absmax=0.0156) ----
// Strict (non-contractable) f32 mul/add via inline asm; greedy via
// reciprocal-multiply (XLA rewrites x/3 -> x*(1/3)); rintf half-even.
// Do not change: each prior ordering variant flipped ~50 bins and failed.
__device__ __forceinline__ float fmul_strict(float a, float b) {
    float r;
    asm volatile("v_mul_f32 %0, %1, %2" : "=v"(r) : "v"(a), "v"(b));
    return r;
}
__device__ __forceinline__ float fadd_strict(float a, float b) {
    float r;
    asm volatile("v_add_f32 %0, %1, %2" : "=v"(r) : "v"(a), "v"(b));
    return r;
}

__device__ __forceinline__ void lattice_point(
    const float* __restrict__ t,   // 9 floats, row-major trans_mat[b]
    float p0, float p1, float p2,
    int& gi0, int& gi1, int& rc0, int& rc1)
{
    float e0 = fadd_strict(fadd_strict(fmul_strict(t[0], p0), fmul_strict(t[1], p1)), fmul_strict(t[2], p2));
    float e1 = fadd_strict(fadd_strict(fmul_strict(t[3], p0), fmul_strict(t[4], p1)), fmul_strict(t[5], p2));
    float e2 = fadd_strict(fadd_strict(fmul_strict(t[6], p0), fmul_strict(t[7], p1)), fmul_strict(t[8], p2));

    // greedy = round(e * (1/3)) * 3
    float g0 = __fmul_rn(rintf(__fmul_rn(e0, C3INV)), 3.0f);
    float g1 = __fmul_rn(rintf(__fmul_rn(e1, C3INV)), 3.0f);
    float g2 = __fmul_rn(rintf(__fmul_rn(e2, C3INV)), 3.0f);

    // emg = elevated - greedy (exact); rank = stable descending argsort pos
    float m0 = e0 - g0, m1 = e1 - g1, m2 = e2 - g2;
    int r0 = (int)(m1 > m0) + (int)(m2 > m0);
    int r1 = (int)(m0 >= m1) + (int)(m2 > m1);

    gi0 = (int)g0;
    gi1 = (int)g1;

    // rs = (g0+g1+g2)/3 : exact integer (sum is a multiple of 3)
    const int irs = (gi0 + gi1 + (int)g2) / 3;

    if (irs > 0) {
        if (r0 >= 3 - irs) { gi0 -= 3; r0 -= 3; }
        if (r1 >= 3 - irs) { gi1 -= 3; r1 -= 3; }
    } else if (irs < 0) {
        if (r0 < -irs) { gi0 += 3; r0 += 3; }
        if (r1 < -irs) { gi1 += 3; r1 += 3; }
    }
    r0 += irs;
    r1 += irs;

    // CANONICAL[rank] gather: wrap negative once, clamp to [0,2];
    // min_k CANONICAL[row][k] == -row
    if (r0 < 0) r0 += 3;
    if (r1 < 0) r1 += 3;
    rc0 = min(2, max(0, r0));
    rc1 = min(2, max(0, r1));
}

// Pass A: per-batch min over n of (greedy_c - row_c), c in {0,1}
__global__ __launch_bounds__(256) void kmin_kernel(
    const float* __restrict__ pc, const float* __restrict__ tmg,
    int* __restrict__ mins)
{
    const int b = blockIdx.y;
    const int n = blockIdx.x * 256 + threadIdx.x;

    __shared__ float t[9];
    if (threadIdx.x < 9) t[threadIdx.x] = tmg[b * 9 + threadIdx.x];
    __syncthreads();

    const float p0 = pc[(b * 3 + 0) * NPTS + n];
    const float p1 = pc[(b * 3 + 1) * NPTS + n];
    const float p2 = pc[(b * 3 + 2) * NPTS + n];

    int gi0, gi1, rc0, rc1;
    lattice_point(t, p0, p1, p2, gi0, gi1, rc0, rc1);

    int km0 = gi0 - rc0;
    int km1 = gi1 - rc1;

#pragma unroll
    for (int off = 32; off > 0; off >>= 1) {
        km0 = min(km0, __shfl_down(km0, off));
        km1 = min(km1, __shfl_down(km1, off));
    }
    __shared__ int s0[4], s1[4];
    const int wid = threadIdx.x >> 6;
    const int lid = threadIdx.x & 63;
    if (lid == 0) { s0[wid] = km0; s1[wid] = km1; }
    __syncthreads();
    if (threadIdx.x == 0) {
        int m0 = min(min(s0[0], s0[1]), min(s0[2], s0[3]));
        int m1 = min(min(s1[0], s1[1]), min(s1[2], s1[3]));
        atomicMin(&mins[b * 2 + 0], m0);
        atomicMin(&mins[b * 2 + 1], m1);
    }
}

// Pass B (restructured): LDS-privatized histogram, exclusive ownership.
// Grid = (8 x-tiles, 32 batches); each block owns output columns
// x in [tile*16, tile*16+16) of batch b, scans ALL the batch's points
// (lattice recompute is free: VALUBusy was 1.4%), ds_add's in-tile hits,
// then plain coalesced stores. Zero global atomics; no output memset needed
// (every cell of the output is stored exactly once).
#define TILE_X 16
#define HIST_F (128 * TILE_X * 3)   // 6144 floats = 24.6 KB

__global__ __launch_bounds__(1024) void splat_kernel(
    const float* __restrict__ pc, const float* __restrict__ feat,
    const float* __restrict__ tmg, const int* __restrict__ mins,
    float* __restrict__ out)
{
    const int tile = blockIdx.x;      // 0..7
    const int b    = blockIdx.y;      // 0..31
    const int tid  = threadIdx.x;     // 0..1023
    const int x0   = tile * TILE_X;

    __shared__ float t[9];
    __shared__ float hist[HIST_F];
    if (tid < 9) t[tid] = tmg[b * 9 + tid];
#pragma unroll
    for (int i = tid; i < HIST_F; i += 1024) hist[i] = 0.0f;
    __syncthreads();

    const int off0 = mins[b * 2 + 0];
    const int off1 = mins[b * 2 + 1];

    const float* pcb = pc   + (size_t)b * 3 * NPTS;
    const float* ftb = feat + (size_t)b * 3 * NPTS;

    for (int n = tid; n < NPTS; n += 1024) {
        const float p0 = pcb[0 * NPTS + n];
        const float p1 = pcb[1 * NPTS + n];
        const float p2 = pcb[2 * NPTS + n];

        int gi0, gi1, rc0, rc1;
        lattice_point(t, p0, p1, p2, gi0, gi1, rc0, rc1);

        const int c0 = gi0 - off0;   // >= 0 by construction
        const int c1 = gi1 - off1;

        if ((unsigned)c0 < SS && (unsigned)c1 < SS) {
            const int x = c1 / 3;                 // c1 ≡ pick1 (mod 3)
            if ((x >> 4) == tile) {
                const int y = c0 / 3;
                const int base = (y * TILE_X + (x - x0)) * 3;
                atomicAdd(&hist[base + 0], ftb[0 * NPTS + n]);
                atomicAdd(&hist[base + 1], ftb[1 * NPTS + n]);
                atomicAdd(&hist[base + 2], ftb[2 * NPTS + n]);
            }
        }
    }
    __syncthreads();

    // Flush: out[((b*128+y)*128+x)*3+ch] ; for this tile the run
    // (x0*3 .. x0*3+47) within each y-row is contiguous, matching
    // hist's (y, rem) linear order -> coalesced 192B runs per row.
#pragma unroll
    for (int idx = tid; idx < HIST_F; idx += 1024) {
        const int y   = idx / (TILE_X * 3);
        const int rem = idx - y * (TILE_X * 3);
        out[(size_t)(b * 128 + y) * 384 + x0 * 3 + rem] = hist[idx];
    }
}

extern "C" void kernel_launch(void* const* d_in, const int* in_sizes, int n_in,
                              void* d_out, int out_size, void* d_ws, size_t ws_size,
                              hipStream_t stream) {
    const float* pc   = (const float*)d_in[0];  // (32,3,65536) f32
    const float* feat = (const float*)d_in[1];  // (32,3,65536) f32
    const float* tm   = (const float*)d_in[2];  // (32,3,3) f32
    float* out = (float*)d_out;                 // (32,128,128,3) f32
    int* mins = (int*)d_ws;                     // 64 ints

    // init mins to ~INT_MAX (0x7F7F7F7F); no output memset needed —
    // splat_kernel stores every output element exactly once.
    hipMemsetAsync(mins, 0x7F, 64 * sizeof(int), stream);

    dim3 gridA(NPTS / 256, NB);
    kmin_kernel<<<gridA, 256, 0, stream>>>(pc, tm, mins);

    dim3 gridB(8, NB);
    splat_kernel<<<gridB, 1024, 0, stream>>>(pc, feat, tm, mins, out);
}

// Round 9
// 190.353 us; speedup vs baseline: 2.6930x; 1.5843x over previous
//
#include <hip/hip_runtime.h>
#include <stdint.h>

// Problem constants (from reference): D1=3, S=384, B=32, N=65536
#define NPTS 65536
#define NB   32
#define SS   384

// RN(1/3) in f32 = 0x3EAAAAAB
#define C3INV 0.333333343267440796f

// ---- LOCKED NUMERICS (R7, passed absmax=0.0156) ----
// Strict (non-contractable) f32 mul/add via inline asm; greedy via
// reciprocal-multiply (XLA rewrites x/3 -> x*(1/3)); rintf half-even.
__device__ __forceinline__ float fmul_strict(float a, float b) {
    float r;
    asm volatile("v_mul_f32 %0, %1, %2" : "=v"(r) : "v"(a), "v"(b));
    return r;
}
__device__ __forceinline__ float fadd_strict(float a, float b) {
    float r;
    asm volatile("v_add_f32 %0, %1, %2" : "=v"(r) : "v"(a), "v"(b));
    return r;
}

__device__ __forceinline__ void lattice_point(
    const float* __restrict__ t,   // 9 floats, row-major trans_mat[b]
    float p0, float p1, float p2,
    int& gi0, int& gi1, int& rc0, int& rc1)
{
    float e0 = fadd_strict(fadd_strict(fmul_strict(t[0], p0), fmul_strict(t[1], p1)), fmul_strict(t[2], p2));
    float e1 = fadd_strict(fadd_strict(fmul_strict(t[3], p0), fmul_strict(t[4], p1)), fmul_strict(t[5], p2));
    float e2 = fadd_strict(fadd_strict(fmul_strict(t[6], p0), fmul_strict(t[7], p1)), fmul_strict(t[8], p2));

    float g0 = __fmul_rn(rintf(__fmul_rn(e0, C3INV)), 3.0f);
    float g1 = __fmul_rn(rintf(__fmul_rn(e1, C3INV)), 3.0f);
    float g2 = __fmul_rn(rintf(__fmul_rn(e2, C3INV)), 3.0f);

    float m0 = e0 - g0, m1 = e1 - g1, m2 = e2 - g2;
    int r0 = (int)(m1 > m0) + (int)(m2 > m0);
    int r1 = (int)(m0 >= m1) + (int)(m2 > m1);

    gi0 = (int)g0;
    gi1 = (int)g1;

    const int irs = (gi0 + gi1 + (int)g2) / 3;

    if (irs > 0) {
        if (r0 >= 3 - irs) { gi0 -= 3; r0 -= 3; }
        if (r1 >= 3 - irs) { gi1 -= 3; r1 -= 3; }
    } else if (irs < 0) {
        if (r0 < -irs) { gi0 += 3; r0 += 3; }
        if (r1 < -irs) { gi1 += 3; r1 += 3; }
    }
    r0 += irs;
    r1 += irs;

    if (r0 < 0) r0 += 3;
    if (r1 < 0) r1 += 3;
    rc0 = min(2, max(0, r0));
    rc1 = min(2, max(0, r1));
}

// ceil(a/3) for any sign (exact)
__device__ __forceinline__ int icl3(int a) {
    return (a >= 0) ? (a + 2) / 3 : -((-a) / 3);
}

// ============================ FAST PATH ============================
// Kernel A: compute lattice once per point; store packed bin to ws;
// block-reduce key-min and PLAIN-STORE per-block partial (no atomics,
// no memset — R8 showed 16K same-line atomicMin = 122 us with all
// pipes <5% busy).
__global__ __launch_bounds__(1024) void bin_kernel(
    const float* __restrict__ pc, const float* __restrict__ tmg,
    uint32_t* __restrict__ bins, int* __restrict__ partial)
{
    const int b   = blockIdx.y;
    const int bx  = blockIdx.x;   // 0..7
    const int tid = threadIdx.x;  // 0..1023

    __shared__ float t[9];
    if (tid < 9) t[tid] = tmg[b * 9 + tid];
    __syncthreads();

    const float* pcb = pc + (size_t)b * 3 * NPTS;
    uint32_t* bb = bins + (size_t)b * NPTS;

    int km0 = 0x7FFFFFFF, km1 = 0x7FFFFFFF;
    const int n0 = bx * 8192;
#pragma unroll
    for (int i = 0; i < 8; ++i) {
        const int n = n0 + i * 1024 + tid;
        const float p0 = pcb[0 * NPTS + n];
        const float p1 = pcb[1 * NPTS + n];
        const float p2 = pcb[2 * NPTS + n];

        int gi0, gi1, rc0, rc1;
        lattice_point(t, p0, p1, p2, gi0, gi1, rc0, rc1);

        // gi is an exact multiple of 3, |gi|/3 << 512 -> fields in [0,1024)
        bb[n] = (uint32_t)(((gi0 / 3 + 512) << 16) | (gi1 / 3 + 512));

        km0 = min(km0, gi0 - rc0);
        km1 = min(km1, gi1 - rc1);
    }

    // wave reduce (64 lanes), then LDS across 16 waves
#pragma unroll
    for (int off = 32; off > 0; off >>= 1) {
        km0 = min(km0, __shfl_down(km0, off));
        km1 = min(km1, __shfl_down(km1, off));
    }
    __shared__ int s0[16], s1[16];
    const int wid = tid >> 6;
    const int lid = tid & 63;
    if (lid == 0) { s0[wid] = km0; s1[wid] = km1; }
    __syncthreads();
    if (tid == 0) {
        int m0 = s0[0], m1 = s1[0];
#pragma unroll
        for (int j = 1; j < 16; ++j) { m0 = min(m0, s0[j]); m1 = min(m1, s1[j]); }
        partial[(b * 8 + bx) * 2 + 0] = m0;
        partial[(b * 8 + bx) * 2 + 1] = m1;
    }
}

// Kernel B: LDS-privatized histogram from precomputed bins.
// Each block owns (batch b, 16-column x-tile); reduces the 8 partial
// mins itself (uniform scalar loads); per point: 1 u32 load + compare,
// conditional 3 feat loads + 3 LDS adds; plain coalesced stores.
#define TILE_X 16
#define HIST_F (128 * TILE_X * 3)   // 6144 floats = 24.6 KB

__global__ __launch_bounds__(1024) void splat_bins_kernel(
    const uint32_t* __restrict__ bins, const float* __restrict__ feat,
    const int* __restrict__ partial, float* __restrict__ out)
{
    const int tile = blockIdx.x;      // 0..7
    const int b    = blockIdx.y;      // 0..31
    const int tid  = threadIdx.x;     // 0..1023

    __shared__ float hist[HIST_F];
#pragma unroll
    for (int i = tid; i < HIST_F; i += 1024) hist[i] = 0.0f;

    int off0 = 0x7FFFFFFF, off1 = 0x7FFFFFFF;
#pragma unroll
    for (int j = 0; j < 8; ++j) {
        off0 = min(off0, partial[(b * 8 + j) * 2 + 0]);
        off1 = min(off1, partial[(b * 8 + j) * 2 + 1]);
    }
    __syncthreads();

    // y = floor((3*s0 - off0)/3) = s0 - ceil(off0/3); same for x.
    const int K0 = 512 + icl3(off0);
    const int K1 = 512 + icl3(off1);

    const uint32_t* bb = bins + (size_t)b * NPTS;
    const float* ftb = feat + (size_t)b * 3 * NPTS;

    for (int n = tid; n < NPTS; n += 1024) {
        const uint32_t u = bb[n];
        const int y = (int)(u >> 16) - K0;       // >= 0 by construction
        const int x = (int)(u & 0xFFFFu) - K1;   // >= 0 by construction
        // y<128 == (c0<384); (x>>4)==tile subsumes x<128
        if (y < 128 && (x >> 4) == tile) {
            const int base = (y * TILE_X + (x & 15)) * 3;
            atomicAdd(&hist[base + 0], ftb[0 * NPTS + n]);
            atomicAdd(&hist[base + 1], ftb[1 * NPTS + n]);
            atomicAdd(&hist[base + 2], ftb[2 * NPTS + n]);
        }
    }
    __syncthreads();

    const int x0 = tile * TILE_X;
#pragma unroll
    for (int idx = tid; idx < HIST_F; idx += 1024) {
        const int y   = idx / (TILE_X * 3);
        const int rem = idx - y * (TILE_X * 3);
        out[(size_t)(b * 128 + y) * 384 + x0 * 3 + rem] = hist[idx];
    }
}

// ========================= FALLBACK PATH ==========================
// Used only if ws_size < bins+partial. Reduced-atomic kmin (512 atomics
// instead of 16K) + R8 recompute splat. Needs 64 ints of ws.
__global__ __launch_bounds__(1024) void kmin2_kernel(
    const float* __restrict__ pc, const float* __restrict__ tmg,
    int* __restrict__ mins)
{
    const int b = blockIdx.y, bx = blockIdx.x, tid = threadIdx.x;
    __shared__ float t[9];
    if (tid < 9) t[tid] = tmg[b * 9 + tid];
    __syncthreads();

    const float* pcb = pc + (size_t)b * 3 * NPTS;
    int km0 = 0x7FFFFFFF, km1 = 0x7FFFFFFF;
    const int n0 = bx * 8192;
#pragma unroll
    for (int i = 0; i < 8; ++i) {
        const int n = n0 + i * 1024 + tid;
        int gi0, gi1, rc0, rc1;
        lattice_point(t, pcb[n], pcb[NPTS + n], pcb[2 * NPTS + n], gi0, gi1, rc0, rc1);
        km0 = min(km0, gi0 - rc0);
        km1 = min(km1, gi1 - rc1);
    }
#pragma unroll
    for (int off = 32; off > 0; off >>= 1) {
        km0 = min(km0, __shfl_down(km0, off));
        km1 = min(km1, __shfl_down(km1, off));
    }
    __shared__ int s0[16], s1[16];
    if ((tid & 63) == 0) { s0[tid >> 6] = km0; s1[tid >> 6] = km1; }
    __syncthreads();
    if (tid == 0) {
        int m0 = s0[0], m1 = s1[0];
#pragma unroll
        for (int j = 1; j < 16; ++j) { m0 = min(m0, s0[j]); m1 = min(m1, s1[j]); }
        atomicMin(&mins[b * 2 + 0], m0);
        atomicMin(&mins[b * 2 + 1], m1);
    }
}

__global__ __launch_bounds__(1024) void splat_recompute_kernel(
    const float* __restrict__ pc, const float* __restrict__ feat,
    const float* __restrict__ tmg, const int* __restrict__ mins,
    float* __restrict__ out)
{
    const int tile = blockIdx.x, b = blockIdx.y, tid = threadIdx.x;
    const int x0 = tile * TILE_X;

    __shared__ float t[9];
    __shared__ float hist[HIST_F];
    if (tid < 9) t[tid] = tmg[b * 9 + tid];
#pragma unroll
    for (int i = tid; i < HIST_F; i += 1024) hist[i] = 0.0f;
    __syncthreads();

    const int off0 = mins[b * 2 + 0];
    const int off1 = mins[b * 2 + 1];
    const float* pcb = pc + (size_t)b * 3 * NPTS;
    const float* ftb = feat + (size_t)b * 3 * NPTS;

    for (int n = tid; n < NPTS; n += 1024) {
        int gi0, gi1, rc0, rc1;
        lattice_point(t, pcb[n], pcb[NPTS + n], pcb[2 * NPTS + n], gi0, gi1, rc0, rc1);
        const int c0 = gi0 - off0;
        const int c1 = gi1 - off1;
        if ((unsigned)c0 < SS && (unsigned)c1 < SS) {
            const int x = c1 / 3;
            if ((x >> 4) == tile) {
                const int y = c0 / 3;
                const int base = (y * TILE_X + (x - x0)) * 3;
                atomicAdd(&hist[base + 0], ftb[0 * NPTS + n]);
                atomicAdd(&hist[base + 1], ftb[1 * NPTS + n]);
                atomicAdd(&hist[base + 2], ftb[2 * NPTS + n]);
            }
        }
    }
    __syncthreads();
#pragma unroll
    for (int idx = tid; idx < HIST_F; idx += 1024) {
        const int y   = idx / (TILE_X * 3);
        const int rem = idx - y * (TILE_X * 3);
        out[(size_t)(b * 128 + y) * 384 + x0 * 3 + rem] = hist[idx];
    }
}

extern "C" void kernel_launch(void* const* d_in, const int* in_sizes, int n_in,
                              void* d_out, int out_size, void* d_ws, size_t ws_size,
                              hipStream_t stream) {
    const float* pc   = (const float*)d_in[0];  // (32,3,65536) f32
    const float* feat = (const float*)d_in[1];  // (32,3,65536) f32
    const float* tm   = (const float*)d_in[2];  // (32,3,3) f32
    float* out = (float*)d_out;                 // (32,128,128,3) f32

    const size_t bins_bytes = (size_t)NB * NPTS * sizeof(uint32_t);  // 8 MB
    const size_t need = bins_bytes + 512 * sizeof(int);

    dim3 grid(8, NB);
    if (ws_size >= need) {
        uint32_t* bins = (uint32_t*)d_ws;
        int* partial = (int*)((char*)d_ws + bins_bytes);
        bin_kernel<<<grid, 1024, 0, stream>>>(pc, tm, bins, partial);
        splat_bins_kernel<<<grid, 1024, 0, stream>>>(bins, feat, partial, out);
    } else {
        int* mins = (int*)d_ws;  // 64 ints
        hipMemsetAsync(mins, 0x7F, 64 * sizeof(int), stream);
        kmin2_kernel<<<grid, 1024, 0, stream>>>(pc, tm, mins);
        splat_recompute_kernel<<<grid, 1024, 0, stream>>>(pc, feat, tm, mins, out);
    }
}

// Round 10
// 169.170 us; speedup vs baseline: 3.0302x; 1.1252x over previous
//
#include <hip/hip_runtime.h>
#include <stdint.h>

// Problem constants (from reference): D1=3, S=384, B=32, N=65536
#define NPTS 65536
#define NB   32
#define SS   384

// RN(1/3) in f32 = 0x3EAAAAAB
#define C3INV 0.333333343267440796f

// ---- LOCKED NUMERICS (R7, passed absmax<=0.0156) ----
// Strict (non-contractable) f32 mul/add via inline asm; greedy via
// reciprocal-multiply (XLA rewrites x/3 -> x*(1/3)); rintf half-even.
__device__ __forceinline__ float fmul_strict(float a, float b) {
    float r;
    asm volatile("v_mul_f32 %0, %1, %2" : "=v"(r) : "v"(a), "v"(b));
    return r;
}
__device__ __forceinline__ float fadd_strict(float a, float b) {
    float r;
    asm volatile("v_add_f32 %0, %1, %2" : "=v"(r) : "v"(a), "v"(b));
    return r;
}

__device__ __forceinline__ void lattice_point(
    const float* __restrict__ t,   // 9 floats, row-major trans_mat[b]
    float p0, float p1, float p2,
    int& gi0, int& gi1, int& rc0, int& rc1)
{
    float e0 = fadd_strict(fadd_strict(fmul_strict(t[0], p0), fmul_strict(t[1], p1)), fmul_strict(t[2], p2));
    float e1 = fadd_strict(fadd_strict(fmul_strict(t[3], p0), fmul_strict(t[4], p1)), fmul_strict(t[5], p2));
    float e2 = fadd_strict(fadd_strict(fmul_strict(t[6], p0), fmul_strict(t[7], p1)), fmul_strict(t[8], p2));

    float g0 = __fmul_rn(rintf(__fmul_rn(e0, C3INV)), 3.0f);
    float g1 = __fmul_rn(rintf(__fmul_rn(e1, C3INV)), 3.0f);
    float g2 = __fmul_rn(rintf(__fmul_rn(e2, C3INV)), 3.0f);

    float m0 = e0 - g0, m1 = e1 - g1, m2 = e2 - g2;
    int r0 = (int)(m1 > m0) + (int)(m2 > m0);
    int r1 = (int)(m0 >= m1) + (int)(m2 > m1);

    gi0 = (int)g0;
    gi1 = (int)g1;

    const int irs = (gi0 + gi1 + (int)g2) / 3;

    if (irs > 0) {
        if (r0 >= 3 - irs) { gi0 -= 3; r0 -= 3; }
        if (r1 >= 3 - irs) { gi1 -= 3; r1 -= 3; }
    } else if (irs < 0) {
        if (r0 < -irs) { gi0 += 3; r0 += 3; }
        if (r1 < -irs) { gi1 += 3; r1 += 3; }
    }
    r0 += irs;
    r1 += irs;

    if (r0 < 0) r0 += 3;
    if (r1 < 0) r1 += 3;
    rc0 = min(2, max(0, r0));
    rc1 = min(2, max(0, r1));
}

// ceil(a/3) for any sign (exact)
__device__ __forceinline__ int icl3(int a) {
    return (a >= 0) ? (a + 2) / 3 : -((-a) / 3);
}

// ============================ FAST PATH ============================
// Kernel A: lattice once per point; packed bin -> ws; block-min
// plain-stored (no atomics).
__global__ __launch_bounds__(1024) void bin_kernel(
    const float* __restrict__ pc, const float* __restrict__ tmg,
    uint32_t* __restrict__ bins, int* __restrict__ partial)
{
    const int b   = blockIdx.y;
    const int bx  = blockIdx.x;   // 0..7
    const int tid = threadIdx.x;  // 0..1023

    __shared__ float t[9];
    if (tid < 9) t[tid] = tmg[b * 9 + tid];
    __syncthreads();

    const float* pcb = pc + (size_t)b * 3 * NPTS;
    uint32_t* bb = bins + (size_t)b * NPTS;

    int km0 = 0x7FFFFFFF, km1 = 0x7FFFFFFF;
    const int n0 = bx * 8192;
#pragma unroll
    for (int i = 0; i < 8; ++i) {
        const int n = n0 + i * 1024 + tid;
        const float p0 = pcb[0 * NPTS + n];
        const float p1 = pcb[1 * NPTS + n];
        const float p2 = pcb[2 * NPTS + n];

        int gi0, gi1, rc0, rc1;
        lattice_point(t, p0, p1, p2, gi0, gi1, rc0, rc1);

        // gi is an exact multiple of 3 (exact /3 even for negatives)
        bb[n] = (uint32_t)(((gi0 / 3 + 512) << 16) | (gi1 / 3 + 512));

        km0 = min(km0, gi0 - rc0);
        km1 = min(km1, gi1 - rc1);
    }

#pragma unroll
    for (int off = 32; off > 0; off >>= 1) {
        km0 = min(km0, __shfl_down(km0, off));
        km1 = min(km1, __shfl_down(km1, off));
    }
    __shared__ int s0[16], s1[16];
    const int wid = tid >> 6;
    const int lid = tid & 63;
    if (lid == 0) { s0[wid] = km0; s1[wid] = km1; }
    __syncthreads();
    if (tid == 0) {
        int m0 = s0[0], m1 = s1[0];
#pragma unroll
        for (int j = 1; j < 16; ++j) { m0 = min(m0, s0[j]); m1 = min(m1, s1[j]); }
        partial[(b * 8 + bx) * 2 + 0] = m0;
        partial[(b * 8 + bx) * 2 + 1] = m1;
    }
}

// Kernel B: LDS-privatized histogram from precomputed bins.
// R10 RESTRUCTURE: ALL loads unconditional & coalesced (bins word +
// 3 feat planes, 4 streams); only the LDS atomic is predicated.
// R9 showed the conditional scattered feat loads were the bottleneck
// (VALUBusy 6.5%, HBM 14%, dur 102us -> pure latency on divergent
// per-line transactions). Grid is (batch, tile) so a batch's 8 tile
// blocks have linear IDs == b (mod 8) -> same XCD under round-robin
// dispatch -> batch working set (~1MB) stays in that XCD's L2.
#define TILE_X 16
#define HIST_F (128 * TILE_X * 3)   // 6144 floats = 24.6 KB

__global__ __launch_bounds__(1024) void splat_bins_kernel(
    const uint32_t* __restrict__ bins, const float* __restrict__ feat,
    const int* __restrict__ partial, float* __restrict__ out)
{
    const int b    = blockIdx.x;      // 0..31  (batch fastest -> XCD co-location)
    const int tile = blockIdx.y;      // 0..7
    const int tid  = threadIdx.x;     // 0..1023

    __shared__ float hist[HIST_F];
#pragma unroll
    for (int i = tid; i < HIST_F; i += 1024) hist[i] = 0.0f;

    int off0 = 0x7FFFFFFF, off1 = 0x7FFFFFFF;
#pragma unroll
    for (int j = 0; j < 8; ++j) {
        off0 = min(off0, partial[(b * 8 + j) * 2 + 0]);
        off1 = min(off1, partial[(b * 8 + j) * 2 + 1]);
    }
    __syncthreads();

    // y = s0 - ceil(off0/3), x = s1 - ceil(off1/3)  (exact; >= 0)
    const int K0 = 512 + icl3(off0);
    const int K1 = 512 + icl3(off1);

    const uint32_t* bb = bins + (size_t)b * NPTS;
    const float* ftb = feat + (size_t)b * 3 * NPTS;

#pragma unroll 4
    for (int i = 0; i < NPTS / 1024; ++i) {
        const int n = i * 1024 + tid;
        // unconditional coalesced streams
        const uint32_t u = bb[n];
        const float f0 = ftb[0 * NPTS + n];
        const float f1 = ftb[1 * NPTS + n];
        const float f2 = ftb[2 * NPTS + n];

        const int y = (int)(u >> 16) - K0;
        const int x = (int)(u & 0xFFFFu) - K1;
        // y<128 == (c0<384); (x>>4)==tile subsumes 0<=x<128
        if (y < 128 && (x >> 4) == tile) {
            const int base = (y * TILE_X + (x & 15)) * 3;
            atomicAdd(&hist[base + 0], f0);
            atomicAdd(&hist[base + 1], f1);
            atomicAdd(&hist[base + 2], f2);
        }
    }
    __syncthreads();

    const int x0 = tile * TILE_X;
#pragma unroll
    for (int idx = tid; idx < HIST_F; idx += 1024) {
        const int y   = idx / (TILE_X * 3);
        const int rem = idx - y * (TILE_X * 3);
        out[(size_t)(b * 128 + y) * 384 + x0 * 3 + rem] = hist[idx];
    }
}

// ========================= FALLBACK PATH ==========================
// Only if ws_size < bins+partial (never observed). 64 ints of ws.
__global__ __launch_bounds__(1024) void kmin2_kernel(
    const float* __restrict__ pc, const float* __restrict__ tmg,
    int* __restrict__ mins)
{
    const int b = blockIdx.y, bx = blockIdx.x, tid = threadIdx.x;
    __shared__ float t[9];
    if (tid < 9) t[tid] = tmg[b * 9 + tid];
    __syncthreads();

    const float* pcb = pc + (size_t)b * 3 * NPTS;
    int km0 = 0x7FFFFFFF, km1 = 0x7FFFFFFF;
    const int n0 = bx * 8192;
#pragma unroll
    for (int i = 0; i < 8; ++i) {
        const int n = n0 + i * 1024 + tid;
        int gi0, gi1, rc0, rc1;
        lattice_point(t, pcb[n], pcb[NPTS + n], pcb[2 * NPTS + n], gi0, gi1, rc0, rc1);
        km0 = min(km0, gi0 - rc0);
        km1 = min(km1, gi1 - rc1);
    }
#pragma unroll
    for (int off = 32; off > 0; off >>= 1) {
        km0 = min(km0, __shfl_down(km0, off));
        km1 = min(km1, __shfl_down(km1, off));
    }
    __shared__ int s0[16], s1[16];
    if ((tid & 63) == 0) { s0[tid >> 6] = km0; s1[tid >> 6] = km1; }
    __syncthreads();
    if (tid == 0) {
        int m0 = s0[0], m1 = s1[0];
#pragma unroll
        for (int j = 1; j < 16; ++j) { m0 = min(m0, s0[j]); m1 = min(m1, s1[j]); }
        atomicMin(&mins[b * 2 + 0], m0);
        atomicMin(&mins[b * 2 + 1], m1);
    }
}

__global__ __launch_bounds__(1024) void splat_recompute_kernel(
    const float* __restrict__ pc, const float* __restrict__ feat,
    const float* __restrict__ tmg, const int* __restrict__ mins,
    float* __restrict__ out)
{
    const int tile = blockIdx.x, b = blockIdx.y, tid = threadIdx.x;
    const int x0 = tile * TILE_X;

    __shared__ float t[9];
    __shared__ float hist[HIST_F];
    if (tid < 9) t[tid] = tmg[b * 9 + tid];
#pragma unroll
    for (int i = tid; i < HIST_F; i += 1024) hist[i] = 0.0f;
    __syncthreads();

    const int off0 = mins[b * 2 + 0];
    const int off1 = mins[b * 2 + 1];
    const float* pcb = pc + (size_t)b * 3 * NPTS;
    const float* ftb = feat + (size_t)b * 3 * NPTS;

    for (int n = tid; n < NPTS; n += 1024) {
        int gi0, gi1, rc0, rc1;
        lattice_point(t, pcb[n], pcb[NPTS + n], pcb[2 * NPTS + n], gi0, gi1, rc0, rc1);
        const int c0 = gi0 - off0;
        const int c1 = gi1 - off1;
        if ((unsigned)c0 < SS && (unsigned)c1 < SS) {
            const int x = c1 / 3;
            if ((x >> 4) == tile) {
                const int y = c0 / 3;
                const int base = (y * TILE_X + (x - x0)) * 3;
                atomicAdd(&hist[base + 0], ftb[0 * NPTS + n]);
                atomicAdd(&hist[base + 1], ftb[1 * NPTS + n]);
                atomicAdd(&hist[base + 2], ftb[2 * NPTS + n]);
            }
        }
    }
    __syncthreads();
#pragma unroll
    for (int idx = tid; idx < HIST_F; idx += 1024) {
        const int y   = idx / (TILE_X * 3);
        const int rem = idx - y * (TILE_X * 3);
        out[(size_t)(b * 128 + y) * 384 + x0 * 3 + rem] = hist[idx];
    }
}

extern "C" void kernel_launch(void* const* d_in, const int* in_sizes, int n_in,
                              void* d_out, int out_size, void* d_ws, size_t ws_size,
                              hipStream_t stream) {
    const float* pc   = (const float*)d_in[0];  // (32,3,65536) f32
    const float* feat = (const float*)d_in[1];  // (32,3,65536) f32
    const float* tm   = (const float*)d_in[2];  // (32,3,3) f32
    float* out = (float*)d_out;                 // (32,128,128,3) f32

    const size_t bins_bytes = (size_t)NB * NPTS * sizeof(uint32_t);  // 8 MB
    const size_t need = bins_bytes + 512 * sizeof(int);

    if (ws_size >= need) {
        uint32_t* bins = (uint32_t*)d_ws;
        int* partial = (int*)((char*)d_ws + bins_bytes);
        dim3 gridA(8, NB);
        bin_kernel<<<gridA, 1024, 0, stream>>>(pc, tm, bins, partial);
        dim3 gridB(NB, 8);   // batch fastest -> same-batch tiles on one XCD
        splat_bins_kernel<<<gridB, 1024, 0, stream>>>(bins, feat, partial, out);
    } else {
        int* mins = (int*)d_ws;  // 64 ints
        hipMemsetAsync(mins, 0x7F, 64 * sizeof(int), stream);
        dim3 grid(8, NB);
        kmin2_kernel<<<grid, 1024, 0, stream>>>(pc, tm, mins);
        dim3 gridB2(8, NB);
        splat_recompute_kernel<<<gridB2, 1024, 0, stream>>>(pc, feat, tm, mins, out);
    }
}

// Round 11
// 168.443 us; speedup vs baseline: 3.0433x; 1.0043x over previous
//
#include <hip/hip_runtime.h>
#include <stdint.h>

// Problem constants (from reference): D1=3, S=384, B=32, N=65536
#define NPTS 65536
#define NB   32
#define SS   384

// RN(1/3) in f32 = 0x3EAAAAAB
#define C3INV 0.333333343267440796f

// ---- LOCKED NUMERICS (R7, passed absmax<=0.0156) ----
__device__ __forceinline__ float fmul_strict(float a, float b) {
    float r;
    asm volatile("v_mul_f32 %0, %1, %2" : "=v"(r) : "v"(a), "v"(b));
    return r;
}
__device__ __forceinline__ float fadd_strict(float a, float b) {
    float r;
    asm volatile("v_add_f32 %0, %1, %2" : "=v"(r) : "v"(a), "v"(b));
    return r;
}

__device__ __forceinline__ void lattice_point(
    const float* __restrict__ t,
    float p0, float p1, float p2,
    int& gi0, int& gi1, int& rc0, int& rc1)
{
    float e0 = fadd_strict(fadd_strict(fmul_strict(t[0], p0), fmul_strict(t[1], p1)), fmul_strict(t[2], p2));
    float e1 = fadd_strict(fadd_strict(fmul_strict(t[3], p0), fmul_strict(t[4], p1)), fmul_strict(t[5], p2));
    float e2 = fadd_strict(fadd_strict(fmul_strict(t[6], p0), fmul_strict(t[7], p1)), fmul_strict(t[8], p2));

    float g0 = __fmul_rn(rintf(__fmul_rn(e0, C3INV)), 3.0f);
    float g1 = __fmul_rn(rintf(__fmul_rn(e1, C3INV)), 3.0f);
    float g2 = __fmul_rn(rintf(__fmul_rn(e2, C3INV)), 3.0f);

    float m0 = e0 - g0, m1 = e1 - g1, m2 = e2 - g2;
    int r0 = (int)(m1 > m0) + (int)(m2 > m0);
    int r1 = (int)(m0 >= m1) + (int)(m2 > m1);

    gi0 = (int)g0;
    gi1 = (int)g1;

    const int irs = (gi0 + gi1 + (int)g2) / 3;

    if (irs > 0) {
        if (r0 >= 3 - irs) { gi0 -= 3; r0 -= 3; }
        if (r1 >= 3 - irs) { gi1 -= 3; r1 -= 3; }
    } else if (irs < 0) {
        if (r0 < -irs) { gi0 += 3; r0 += 3; }
        if (r1 < -irs) { gi1 += 3; r1 += 3; }
    }
    r0 += irs;
    r1 += irs;

    if (r0 < 0) r0 += 3;
    if (r1 < 0) r1 += 3;
    rc0 = min(2, max(0, r0));
    rc1 = min(2, max(0, r1));
}

// ceil(a/3) for any sign (exact)
__device__ __forceinline__ int icl3(int a) {
    return (a >= 0) ? (a + 2) / 3 : -((-a) / 3);
}

// ============================ FAST PATH ============================
// Kernel A: lattice once per point; packed bin -> ws; block-min plain-
// stored. R11: 512 blocks (2/CU) for TLP; 4 iterations each.
__global__ __launch_bounds__(1024) void bin_kernel(
    const float* __restrict__ pc, const float* __restrict__ tmg,
    uint32_t* __restrict__ bins, int* __restrict__ partial)
{
    const int bx  = blockIdx.x;   // 0..15
    const int b   = blockIdx.y;
    const int tid = threadIdx.x;

    __shared__ float t[9];
    if (tid < 9) t[tid] = tmg[b * 9 + tid];
    __syncthreads();

    const float* pcb = pc + (size_t)b * 3 * NPTS;
    uint32_t* bb = bins + (size_t)b * NPTS;

    int km0 = 0x7FFFFFFF, km1 = 0x7FFFFFFF;
    const int n0 = bx * 4096;
#pragma unroll
    for (int i = 0; i < 4; ++i) {
        const int n = n0 + i * 1024 + tid;
        const float p0 = pcb[0 * NPTS + n];
        const float p1 = pcb[1 * NPTS + n];
        const float p2 = pcb[2 * NPTS + n];

        int gi0, gi1, rc0, rc1;
        lattice_point(t, p0, p1, p2, gi0, gi1, rc0, rc1);

        bb[n] = (uint32_t)(((gi0 / 3 + 512) << 16) | (gi1 / 3 + 512));

        km0 = min(km0, gi0 - rc0);
        km1 = min(km1, gi1 - rc1);
    }

#pragma unroll
    for (int off = 32; off > 0; off >>= 1) {
        km0 = min(km0, __shfl_down(km0, off));
        km1 = min(km1, __shfl_down(km1, off));
    }
    __shared__ int s0[16], s1[16];
    if ((tid & 63) == 0) { s0[tid >> 6] = km0; s1[tid >> 6] = km1; }
    __syncthreads();
    if (tid == 0) {
        int m0 = s0[0], m1 = s1[0];
#pragma unroll
        for (int j = 1; j < 16; ++j) { m0 = min(m0, s0[j]); m1 = min(m1, s1[j]); }
        partial[(b * 16 + bx) * 2 + 0] = m0;
        partial[(b * 16 + bx) * 2 + 1] = m1;
    }
}

// Kernel B: LDS-privatized histogram from precomputed bins.
// R11: point-split into 2 chunks -> 512 blocks = 2/CU (32 waves, 100%
// occupancy) at CONSTANT total work (R10 was 1 block/CU, 16 waves,
// latency-exposed: VALUBusy 7.5%, HBM 3.5%). Flush via coalesced global
// atomicAdd into pre-zeroed out (dense, line-local -> ~store rate).
// Swizzle: linear = b + 32*tile + 256*chunk, %8 = b%8 -> same-batch
// blocks share an XCD (R10: FETCH 108->16 MB).
#define TILE_X 16
#define HIST_F (128 * TILE_X * 3)   // 6144 floats = 24.6 KB

__global__ __launch_bounds__(1024) void splat_bins_kernel(
    const uint32_t* __restrict__ bins, const float* __restrict__ feat,
    const int* __restrict__ partial, float* __restrict__ out)
{
    const int b     = blockIdx.x;     // 0..31 (fastest -> XCD co-location)
    const int tile  = blockIdx.y;     // 0..7
    const int chunk = blockIdx.z;     // 0..1
    const int tid   = threadIdx.x;    // 0..1023

    __shared__ float hist[HIST_F];
#pragma unroll
    for (int i = tid; i < HIST_F; i += 1024) hist[i] = 0.0f;

    int off0 = 0x7FFFFFFF, off1 = 0x7FFFFFFF;
#pragma unroll
    for (int j = 0; j < 16; ++j) {
        off0 = min(off0, partial[(b * 16 + j) * 2 + 0]);
        off1 = min(off1, partial[(b * 16 + j) * 2 + 1]);
    }
    __syncthreads();

    // y = s0 - ceil(off0/3), x = s1 - ceil(off1/3)  (exact; >= 0)
    const int K0 = 512 + icl3(off0);
    const int K1 = 512 + icl3(off1);

    const uint32_t* bb = bins + (size_t)b * NPTS + (size_t)chunk * (NPTS / 2);
    const float* ftb = feat + (size_t)b * 3 * NPTS + (size_t)chunk * (NPTS / 2);

#pragma unroll 8
    for (int i = 0; i < (NPTS / 2) / 1024; ++i) {
        const int n = i * 1024 + tid;
        // unconditional coalesced streams
        const uint32_t u = bb[n];
        const float f0 = ftb[0 * NPTS + n];
        const float f1 = ftb[1 * NPTS + n];
        const float f2 = ftb[2 * NPTS + n];

        const int y = (int)(u >> 16) - K0;
        const int x = (int)(u & 0xFFFFu) - K1;
        // y<128 == (c0<384); (x>>4)==tile subsumes 0<=x<128
        if (y < 128 && (x >> 4) == tile) {
            const int base = (y * TILE_X + (x & 15)) * 3;
            atomicAdd(&hist[base + 0], f0);
            atomicAdd(&hist[base + 1], f1);
            atomicAdd(&hist[base + 2], f2);
        }
    }
    __syncthreads();

    // Flush: dense coalesced global atomics into pre-zeroed out.
    const int x0 = tile * TILE_X;
#pragma unroll
    for (int idx = tid; idx < HIST_F; idx += 1024) {
        const int y   = idx / (TILE_X * 3);
        const int rem = idx - y * (TILE_X * 3);
        atomicAdd(&out[(size_t)(b * 128 + y) * 384 + x0 * 3 + rem], hist[idx]);
    }
}

// ========================= FALLBACK PATH ==========================
// Only if ws_size < bins+partial (never observed). 64 ints of ws.
__global__ __launch_bounds__(1024) void kmin2_kernel(
    const float* __restrict__ pc, const float* __restrict__ tmg,
    int* __restrict__ mins)
{
    const int b = blockIdx.y, bx = blockIdx.x, tid = threadIdx.x;
    __shared__ float t[9];
    if (tid < 9) t[tid] = tmg[b * 9 + tid];
    __syncthreads();

    const float* pcb = pc + (size_t)b * 3 * NPTS;
    int km0 = 0x7FFFFFFF, km1 = 0x7FFFFFFF;
    const int n0 = bx * 8192;
#pragma unroll
    for (int i = 0; i < 8; ++i) {
        const int n = n0 + i * 1024 + tid;
        int gi0, gi1, rc0, rc1;
        lattice_point(t, pcb[n], pcb[NPTS + n], pcb[2 * NPTS + n], gi0, gi1, rc0, rc1);
        km0 = min(km0, gi0 - rc0);
        km1 = min(km1, gi1 - rc1);
    }
#pragma unroll
    for (int off = 32; off > 0; off >>= 1) {
        km0 = min(km0, __shfl_down(km0, off));
        km1 = min(km1, __shfl_down(km1, off));
    }
    __shared__ int s0[16], s1[16];
    if ((tid & 63) == 0) { s0[tid >> 6] = km0; s1[tid >> 6] = km1; }
    __syncthreads();
    if (tid == 0) {
        int m0 = s0[0], m1 = s1[0];
#pragma unroll
        for (int j = 1; j < 16; ++j) { m0 = min(m0, s0[j]); m1 = min(m1, s1[j]); }
        atomicMin(&mins[b * 2 + 0], m0);
        atomicMin(&mins[b * 2 + 1], m1);
    }
}

__global__ __launch_bounds__(1024) void splat_recompute_kernel(
    const float* __restrict__ pc, const float* __restrict__ feat,
    const float* __restrict__ tmg, const int* __restrict__ mins,
    float* __restrict__ out)
{
    const int tile = blockIdx.x, b = blockIdx.y, tid = threadIdx.x;
    const int x0 = tile * TILE_X;

    __shared__ float t[9];
    __shared__ float hist[HIST_F];
    if (tid < 9) t[tid] = tmg[b * 9 + tid];
#pragma unroll
    for (int i = tid; i < HIST_F; i += 1024) hist[i] = 0.0f;
    __syncthreads();

    const int off0 = mins[b * 2 + 0];
    const int off1 = mins[b * 2 + 1];
    const float* pcb = pc + (size_t)b * 3 * NPTS;
    const float* ftb = feat + (size_t)b * 3 * NPTS;

    for (int n = tid; n < NPTS; n += 1024) {
        int gi0, gi1, rc0, rc1;
        lattice_point(t, pcb[n], pcb[NPTS + n], pcb[2 * NPTS + n], gi0, gi1, rc0, rc1);
        const int c0 = gi0 - off0;
        const int c1 = gi1 - off1;
        if ((unsigned)c0 < SS && (unsigned)c1 < SS) {
            const int x = c1 / 3;
            if ((x >> 4) == tile) {
                const int y = c0 / 3;
                const int base = (y * TILE_X + (x - x0)) * 3;
                atomicAdd(&hist[base + 0], ftb[0 * NPTS + n]);
                atomicAdd(&hist[base + 1], ftb[1 * NPTS + n]);
                atomicAdd(&hist[base + 2], ftb[2 * NPTS + n]);
            }
        }
    }
    __syncthreads();
#pragma unroll
    for (int idx = tid; idx < HIST_F; idx += 1024) {
        const int y   = idx / (TILE_X * 3);
        const int rem = idx - y * (TILE_X * 3);
        out[(size_t)(b * 128 + y) * 384 + x0 * 3 + rem] = hist[idx];
    }
}

extern "C" void kernel_launch(void* const* d_in, const int* in_sizes, int n_in,
                              void* d_out, int out_size, void* d_ws, size_t ws_size,
                              hipStream_t stream) {
    const float* pc   = (const float*)d_in[0];  // (32,3,65536) f32
    const float* feat = (const float*)d_in[1];  // (32,3,65536) f32
    const float* tm   = (const float*)d_in[2];  // (32,3,3) f32
    float* out = (float*)d_out;                 // (32,128,128,3) f32

    const size_t bins_bytes = (size_t)NB * NPTS * sizeof(uint32_t);  // 8 MB
    const size_t need = bins_bytes + 1024 * sizeof(int);

    if (ws_size >= need) {
        uint32_t* bins = (uint32_t*)d_ws;
        int* partial = (int*)((char*)d_ws + bins_bytes);

        // out must be zero: splat flush is atomicAdd (2 chunks per cell)
        hipMemsetAsync(out, 0, (size_t)out_size * sizeof(float), stream);

        dim3 gridA(16, NB);
        bin_kernel<<<gridA, 1024, 0, stream>>>(pc, tm, bins, partial);
        dim3 gridB(NB, 8, 2);   // b fastest -> same-batch tiles on one XCD
        splat_bins_kernel<<<gridB, 1024, 0, stream>>>(bins, feat, partial, out);
    } else {
        int* mins = (int*)d_ws;  // 64 ints
        hipMemsetAsync(mins, 0x7F, 64 * sizeof(int), stream);
        dim3 grid(8, NB);
        kmin2_kernel<<<grid, 1024, 0, stream>>>(pc, tm, mins);
        dim3 gridB2(8, NB);
        splat_recompute_kernel<<<gridB2, 1024, 0, stream>>>(pc, feat, tm, mins, out);
    }
}